// Round 6
// baseline (154.361 us; speedup 1.0000x reference)
//
#include <hip/hip_runtime.h>

// AliasFreeActivation fused kernel, v6: plane-pair float2 (packed v_pk_fma_f32,
// proven in v4: busy 32us vs scalar v5's 56us) + 512-thread blocks so the
// 51.7KB LDS overlay still allows 3 blocks/CU = 24 waves/CU = 6/SIMD (v5's
// occupancy). v4 = packed but 3 waves/SIMD (44% idle); v5 = 6 waves but
// scalar. v6 = both.
//
// Math (identical to v1..v5, all passed):
//   upH -> (upW + leaky + downW fused) -> downH, crop folded in.
//   hi[l] = sum_{t=0..5} tH[m0-1+t]*up[c0-4t], m0=(l+5)>>2, c0=20+((l+1)&3)
//   out[o] = sum_k hl[2o+k]*dn[11-k]
//
// Pass remapping for 512 threads (all filter indices stay compile-time):
//  P1: 15 segs x 8 rows (510 thr); 8*s1 % 4 == 0 keeps rel compile-time.
//  P2: 4 segs x 13 outputs (456 thr); loop starts at L0 = 26p - 2(p&1)
//      (multiple of 4) -> single phase for all p; odd p scatters into
//      acc[1..13] of acc[14], chosen at writeback only.
//  P3: 8 segs x 7 rows (416 thr); t2 padded to 122 rows; stores row-guarded.

typedef float v2f __attribute__((ext_vector_type(2)));

static __device__ __forceinline__ v2f vsplat(float s) { v2f v; v.x = s; v.y = s; return v; }
#define VFMA(A, S, C) __builtin_elementwise_fma((A), vsplat(S), (C))

// ---- pass 2: sample j' (rel = ((j'+5)>>2)-1), leaky, scatter into acc[14] ----
#define SCATTER(J, hv)                                                        \
    _Pragma("unroll")                                                         \
    for (int k = (J) & 1; k <= 11; k += 2) {                                  \
        if ((J) - k >= 0 && (((J) - k) >> 1) < 14)                            \
            acc[((J) - k) >> 1] = VFMA(hv, dn[11 - k], acc[((J) - k) >> 1]);  \
    }

#define DO_J(J, A, B, C, D, E, F)                                             \
    do {                                                                      \
        const int q_ = ((J) + 1) & 3;                                         \
        v2f h_ = (A) * vsplat(up[20 + q_]);                                   \
        h_ = VFMA((B), up[16 + q_], h_);                                      \
        h_ = VFMA((C), up[12 + q_], h_);                                      \
        h_ = VFMA((D), up[8 + q_], h_);                                       \
        h_ = VFMA((E), up[4 + q_], h_);                                       \
        h_ = VFMA((F), up[q_], h_);                                           \
        h_ = __builtin_elementwise_max(h_, h_ * vsplat(0.2f));                \
        SCATTER(J, h_);                                                       \
    } while (0)

// Entering GROUP(G): regs hold taps G-1..G+4 in (T0..T5). Load tap G+5 into
// T0 (tap G-1 dead) -> taps G..G+5 in (T1..T5,T0); emit samples 4G-1..4G+2.
#define GROUP(G, T0, T1, T2, T3, T4, T5)                                      \
    do {                                                                      \
        T0 = wbase[(G) + 5];                                                  \
        DO_J(4 * (G) - 1, T1, T2, T3, T4, T5, T0);                            \
        DO_J(4 * (G), T1, T2, T3, T4, T5, T0);                                \
        DO_J(4 * (G) + 1, T1, T2, T3, T4, T5, T0);                            \
        DO_J(4 * (G) + 2, T1, T2, T3, T4, T5, T0);                            \
    } while (0)

// Tail: load tap 14, emit samples 35..37 (rel = 9, taps 9..14).
#define GROUP_TAIL(T0, T1, T2, T3, T4, T5)                                    \
    do {                                                                      \
        T0 = wbase[14];                                                       \
        DO_J(35, T1, T2, T3, T4, T5, T0);                                     \
        DO_J(36, T1, T2, T3, T4, T5, T0);                                     \
        DO_J(37, T1, T2, T3, T4, T5, T0);                                     \
    } while (0)

// ---- pass 3: output row J (oh = 7s+J) from 12 named row-regs ----
#define P3LD(RA, RB, M)                                                       \
    RA = p3b[(M)*53];                                                         \
    RB = p3b[((M) + 1) * 53];

#define P3OUT(J, A, B, C, D, E, F, G, H, I, JJ, K, L)                         \
    do {                                                                      \
        v2f a_ = (A) * vsplat(dn[11]);                                        \
        a_ = VFMA((B), dn[10], a_);                                           \
        a_ = VFMA((C), dn[9], a_);                                            \
        a_ = VFMA((D), dn[8], a_);                                            \
        a_ = VFMA((E), dn[7], a_);                                            \
        a_ = VFMA((F), dn[6], a_);                                            \
        a_ = VFMA((G), dn[5], a_);                                            \
        a_ = VFMA((H), dn[4], a_);                                            \
        a_ = VFMA((I), dn[3], a_);                                            \
        a_ = VFMA((JJ), dn[2], a_);                                           \
        a_ = VFMA((K), dn[1], a_);                                            \
        a_ = VFMA((L), dn[0], a_);                                            \
        const int oh_ = 7 * s + (J);                                          \
        if (oh_ < 52) {                                                       \
            op0[oh_ * 52 + ow] = a_.x;                                        \
            op1[oh_ * 52 + ow] = a_.y;                                        \
        }                                                                     \
    } while (0)

__global__ __launch_bounds__(512, 6)
void afa_kernel(const float* __restrict__ x,
                const float* __restrict__ upf,
                const float* __restrict__ dnf,
                float* __restrict__ out)
{
    // Overlay: tH rows stride 35 (first 3990 v2f), later t2 rows stride 53,
    // padded to 122 rows (pass-3 tail reads rows 114..121, values unused).
    __shared__ v2f buf[122 * 53];   // 51728 bytes -> 3 blocks/CU (8 waves each)

    const int tid = threadIdx.x;
    const size_t q0 = (size_t)blockIdx.x * 2;
    const float* __restrict__ xp0 = x + q0 * 1296;
    const float* __restrict__ xp1 = xp0 + 1296;
    float* __restrict__ op0 = out + q0 * 2704;
    float* __restrict__ op1 = op0 + 2704;

    // filters -> uniform (scalar) registers
    float up[24];
#pragma unroll
    for (int i = 0; i < 24; ++i) up[i] = upf[i];
    float dn[12];
#pragma unroll
    for (int i = 0; i < 12; ++i) dn[i] = dnf[i];

    // ---------------- Pass 1: upsample along H (15 segs x 8 rows) ----------------
    if (tid < 510) {
        const int s1 = tid / 34;        // 0..14
        const int mw = tid % 34 + 1;    // 1..34

        v2f xr[8];                      // x rows 2s1+1 .. 2s1+8 (clamped)
#pragma unroll
        for (int i = 0; i < 8; ++i) {
            int row = 2 * s1 + 1 + i;
            row = row > 35 ? 35 : row;  // clamp; clamped values never used
            xr[i].x = xp0[row * 36 + mw];
            xr[i].y = xp1[row * 36 + mw];
        }
#pragma unroll
        for (int j = 0; j < 8; ++j) {   // lh = 8*s1 + j
            const int rel = ((j + 5) >> 2) - 1;   // compile-time (8s1 % 4 == 0)
            const int c0  = 20 + ((j + 1) & 3);   // compile-time
            v2f a = vsplat(0.f);
#pragma unroll
            for (int t = 0; t < 6; ++t)
                a = VFMA(xr[rel + t], up[c0 - 4 * t], a);
            const int lh = 8 * s1 + j;
            if (lh < 114)
                buf[lh * 35 + (mw - 1)] = a;      // tH region
        }
    }
    __syncthreads();

    // ---- Pass 2: upW + leaky + downW (4 segs x 13 outputs, single phase) ----
    const int  lh   = tid % 114;
    const int  p    = tid / 114;        // 0..3 for tid<456
    const bool act2 = tid < 456;
    v2f acc[14];                        // slot 0 (odd p) / slot 13 (even p) = discard
    if (act2) {
        const int L0 = 26 * p - ((p & 1) << 1);   // sample base, multiple of 4
        const v2f* __restrict__ wbase = &buf[lh * 35 + (L0 >> 2)];
        v2f w0 = wbase[0], w1 = wbase[1], w2 = wbase[2],
            w3 = wbase[3], w4 = wbase[4], w5 = wbase[5];
#pragma unroll
        for (int o = 0; o < 14; ++o) acc[o] = vsplat(0.f);

        DO_J(0, w0, w1, w2, w3, w4, w5);          // rel=0: taps 0..5
        DO_J(1, w0, w1, w2, w3, w4, w5);
        DO_J(2, w0, w1, w2, w3, w4, w5);
        GROUP(1, w0, w1, w2, w3, w4, w5);         // taps 1..6 in (w1..w5,w0)
        GROUP(2, w1, w2, w3, w4, w5, w0);
        GROUP(3, w2, w3, w4, w5, w0, w1);
        GROUP(4, w3, w4, w5, w0, w1, w2);
        GROUP(5, w4, w5, w0, w1, w2, w3);
        GROUP(6, w5, w0, w1, w2, w3, w4);
        GROUP(7, w0, w1, w2, w3, w4, w5);
        GROUP(8, w1, w2, w3, w4, w5, w0);
        GROUP_TAIL(w2, w3, w4, w5, w0, w1);       // tap 14; samples 35..37
    }
    __syncthreads();   // all tH reads complete before any t2 write (overlay)

    if (act2) {
        v2f* __restrict__ tw = &buf[lh * 53 + 13 * p];   // t2 region
        if (p & 1) {
#pragma unroll
            for (int oo = 0; oo < 13; ++oo) tw[oo] = acc[oo + 1];
        } else {
#pragma unroll
            for (int oo = 0; oo < 13; ++oo) tw[oo] = acc[oo];
        }
    }
    __syncthreads();

    // ---------------- Pass 3: downsample along H (8 segs x 7 rows) ----------------
    if (tid < 416) {
        const int ow = tid % 52;
        const int s  = tid / 52;        // 0..7; out rows 7s..7s+6 (guarded)
        const v2f* __restrict__ p3b = &buf[(14 * s) * 53 + ow];  // t2 row 14s+M

        v2f r0, r1, r2, r3, r4, r5, r6, r7, r8, r9, r10, r11;
        P3LD(r0, r1, 0)  P3LD(r2, r3, 2)  P3LD(r4, r5, 4)
        P3LD(r6, r7, 6)  P3LD(r8, r9, 8)  P3LD(r10, r11, 10)

        P3OUT(0, r0, r1, r2, r3, r4, r5, r6, r7, r8, r9, r10, r11);
        P3LD(r0, r1, 12)
        P3OUT(1, r2, r3, r4, r5, r6, r7, r8, r9, r10, r11, r0, r1);
        P3LD(r2, r3, 14)
        P3OUT(2, r4, r5, r6, r7, r8, r9, r10, r11, r0, r1, r2, r3);
        P3LD(r4, r5, 16)
        P3OUT(3, r6, r7, r8, r9, r10, r11, r0, r1, r2, r3, r4, r5);
        P3LD(r6, r7, 18)
        P3OUT(4, r8, r9, r10, r11, r0, r1, r2, r3, r4, r5, r6, r7);
        P3LD(r8, r9, 20)
        P3OUT(5, r10, r11, r0, r1, r2, r3, r4, r5, r6, r7, r8, r9);
        P3LD(r10, r11, 22)
        P3OUT(6, r0, r1, r2, r3, r4, r5, r6, r7, r8, r9, r10, r11);
    }
}

extern "C" void kernel_launch(void* const* d_in, const int* in_sizes, int n_in,
                              void* d_out, int out_size, void* d_ws, size_t ws_size,
                              hipStream_t stream)
{
    const float* x  = (const float*)d_in[0];   // (16,512,36,36)
    const float* up = (const float*)d_in[1];   // (24,)
    const float* dn = (const float*)d_in[2];   // (12,)
    float* out = (float*)d_out;                // (16,512,52,52)

    const int pairs = 16 * 512 / 2;            // 4096 blocks, one plane-pair each
    afa_kernel<<<dim3(pairs), dim3(512), 0, stream>>>(x, up, dn, out);
}

// Round 7
// 143.654 us; speedup vs baseline: 1.0745x; 1.0745x over previous
//
#include <hip/hip_runtime.h>

// AliasFreeActivation fused kernel, v7: single plane per block (v5's proven
// 6-blocks/CU occupancy shape) + INTRA-plane 2-wide packing:
//   P2: adjacent hi samples (j,j+1) packed in v2f -> splat tH data x packed
//       coeff pairs (v_pk_fma_f32); down-scatter packed too (acc2 pairs,
//       horizontal add at writeback). Straddle pairs use 7 zero-padded taps.
//   P1/P3: adjacent even column pairs packed (aligned dwordx2 / ds_read_b64).
// v4 vs v5 vs v6 established: packed math halves busy-time; 256-thr blocks at
// 6 blocks/CU reach 88% busy; 512-thr blocks do not. v7 combines both.
//
// Math identical to v1..v6 (all passed):
//   upH -> (upW + leaky + downW fused) -> downH, crop folded in.
//   hi[l] = sum_t tH[m0-1+t]*up[c0-4t], m0=(l+5)>>2, c0=20+((l+1)&3)
//   out[o] = sum_k hl[2o+k]*dn[11-k]
// LDS overlay: tH rows stride 38 (17.3KB) then t2 rows stride 54 padded to
// 122 rows (26352 B total) -> 6 blocks/CU.

typedef float v2f __attribute__((ext_vector_type(2)));
static __device__ __forceinline__ v2f vsplat(float s){ v2f v; v.x=s; v.y=s; return v; }
#define FMA2(A,B,C) __builtin_elementwise_fma((A),(B),(C))

// ---- P2 sample-pair macros ----
// SCAT: pair (J,J+1) feeds outputs o=J/2-5..J/2 with packed coeff dp[5-i].
#define SCAT(J, hv)                                                           \
    _Pragma("unroll")                                                         \
    for (int i_ = 0; i_ < 6; ++i_) {                                          \
        const int o_ = (J) / 2 - 5 + i_;                                      \
        if (o_ >= 0 && o_ < 26) acc2[o_] = FMA2(hv, dp[5 - i_], acc2[o_]);    \
    }

// ALIGNED pair (J=4G): both samples share taps T0..T5 (rel=G); coeffs ua[t].
#define ALIGNED(J, T0, T1, T2, T3, T4, T5)                                    \
    do {                                                                      \
        v2f h_ = vsplat(T0) * ua[0];                                          \
        h_ = FMA2(vsplat(T1), ua[1], h_);                                     \
        h_ = FMA2(vsplat(T2), ua[2], h_);                                     \
        h_ = FMA2(vsplat(T3), ua[3], h_);                                     \
        h_ = FMA2(vsplat(T4), ua[4], h_);                                     \
        h_ = FMA2(vsplat(T5), ua[5], h_);                                     \
        h_ = __builtin_elementwise_max(h_, h_ * vsplat(0.2f));                \
        SCAT(J, h_);                                                          \
    } while (0)

// STRADDLE pair (J=4G+2): sample J uses taps T0..T5, J+1 uses T1..T6;
// zero-padded packed coeffs us[t] cover both lanes in 7 pk-FMA.
#define STRADDLE(J, T0, T1, T2, T3, T4, T5, T6)                               \
    do {                                                                      \
        v2f h_ = vsplat(T0) * us[0];                                          \
        h_ = FMA2(vsplat(T1), us[1], h_);                                     \
        h_ = FMA2(vsplat(T2), us[2], h_);                                     \
        h_ = FMA2(vsplat(T3), us[3], h_);                                     \
        h_ = FMA2(vsplat(T4), us[4], h_);                                     \
        h_ = FMA2(vsplat(T5), us[5], h_);                                     \
        h_ = FMA2(vsplat(T6), us[6], h_);                                     \
        h_ = __builtin_elementwise_max(h_, h_ * vsplat(0.2f));                \
        SCAT(J, h_);                                                          \
    } while (0)

// One tap-group G: aligned pair (4G,4G+1) on taps G..G+5; load tap G+6;
// straddle pair (4G+2,4G+3) on taps G..G+6.
#define PAIR4(G, T0, T1, T2, T3, T4, T5, T6)                                  \
    do {                                                                      \
        ALIGNED(4 * (G), T0, T1, T2, T3, T4, T5);                             \
        T6 = wbase[(G) + 6];                                                  \
        STRADDLE(4 * (G) + 2, T0, T1, T2, T3, T4, T5, T6);                    \
    } while (0)

// ---- P3 macros (col-pair packed) ----
#define P3LD(RA, RB, M)                                                       \
    RA = *(const v2f*)&p3b[(M) * 54];                                         \
    RB = *(const v2f*)&p3b[((M) + 1) * 54];

#define P3OUT(J, A, B, C, D, E, F, G, H, I, JJ, K, L)                         \
    do {                                                                      \
        v2f a_ = (A) * vsplat(dn[11]);                                        \
        a_ = FMA2((B), vsplat(dn[10]), a_);                                   \
        a_ = FMA2((C), vsplat(dn[9]), a_);                                    \
        a_ = FMA2((D), vsplat(dn[8]), a_);                                    \
        a_ = FMA2((E), vsplat(dn[7]), a_);                                    \
        a_ = FMA2((F), vsplat(dn[6]), a_);                                    \
        a_ = FMA2((G), vsplat(dn[5]), a_);                                    \
        a_ = FMA2((H), vsplat(dn[4]), a_);                                    \
        a_ = FMA2((I), vsplat(dn[3]), a_);                                    \
        a_ = FMA2((JJ), vsplat(dn[2]), a_);                                   \
        a_ = FMA2((K), vsplat(dn[1]), a_);                                    \
        a_ = FMA2((L), vsplat(dn[0]), a_);                                    \
        const int oh_ = 7 * s3 + (J);                                         \
        if (oh_ < 52) *(v2f*)&op[oh_ * 52 + 2 * c3] = a_;                     \
    } while (0)

__global__ __launch_bounds__(256, 6)
void afa_kernel(const float* __restrict__ x,
                const float* __restrict__ upf,
                const float* __restrict__ dnf,
                float* __restrict__ out)
{
    // Overlay: tH rows stride 38 (rows 0..113, cols 0..35) then t2 rows
    // stride 54 (52 cols, padded to 122 rows for P3 tail reads).
    __shared__ float buf[122 * 54];   // 26352 B -> 6 blocks/CU

    const int tid = threadIdx.x;
    const float* __restrict__ xp = x + (size_t)blockIdx.x * 1296;
    float* __restrict__ op = out + (size_t)blockIdx.x * 2704;

    float up[24];
#pragma unroll
    for (int i = 0; i < 24; ++i) up[i] = upf[i];
    float dn[12];
#pragma unroll
    for (int i = 0; i < 12; ++i) dn[i] = dnf[i];

    // ---------------- Pass 1: upsample along H (col-pair packed) ----------------
    // 10 segs x 12 rows (12 % 4 == 0 keeps rel compile-time) x 18 col-pairs.
    if (tid < 180) {
        const int s1 = tid / 18;        // 0..9
        const int c  = tid % 18;        // col pair -> x cols 2c, 2c+1

        v2f xr[9];                      // x rows 3s+1 .. 3s+9 (clamped), col pair
#pragma unroll
        for (int i = 0; i < 9; ++i) {
            int row = 3 * s1 + 1 + i;
            row = row > 35 ? 35 : row;  // clamp; clamped values never used
            xr[i] = *(const v2f*)(xp + row * 36 + 2 * c);   // aligned dwordx2
        }
#pragma unroll
        for (int j = 0; j < 12; ++j) { // lh = 12*s1 + j
            const int rel = ((j + 5) >> 2) - 1;   // 0..3, compile-time
            const int c0  = 20 + ((j + 1) & 3);   // compile-time
            v2f a = vsplat(0.f);
#pragma unroll
            for (int t = 0; t < 6; ++t)
                a = FMA2(xr[rel + t], vsplat(up[c0 - 4 * t]), a);
            const int lh = 12 * s1 + j;
            if (lh < 114)
                *(v2f*)&buf[lh * 38 + 2 * c] = a;           // tH, ds_write_b64
        }
    }
    __syncthreads();

    // ---- Pass 2: upW + leaky + downW, sample-pair packed ----
    const int  lh   = tid % 114;
    const int  p    = tid / 114;        // 0/1 for tid<228
    const bool act2 = tid < 228;
    v2f acc2[26];                       // (even-sample sum, odd-sample sum)
    if (act2) {
        // packed coefficient pairs (uniform; constant-indexed -> SROA)
        v2f ua[6], us[7], dp[6];
#pragma unroll
        for (int t = 0; t < 6; ++t) { ua[t].x = up[21 - 4 * t]; ua[t].y = up[22 - 4 * t]; }
        us[0].x = up[23]; us[0].y = 0.f;
#pragma unroll
        for (int t = 1; t < 6; ++t) { us[t].x = up[23 - 4 * t]; us[t].y = up[24 - 4 * t]; }
        us[6].x = 0.f; us[6].y = up[0];
#pragma unroll
        for (int i = 0; i < 6; ++i) { dp[i].x = dn[11 - 2 * i]; dp[i].y = dn[10 - 2 * i]; }

        const float* __restrict__ wbase = &buf[lh * 38 + 13 * p + 1];
        float w0 = wbase[0], w1 = wbase[1], w2 = wbase[2],
              w3 = wbase[3], w4 = wbase[4], w5 = wbase[5], w6;
#pragma unroll
        for (int o = 0; o < 26; ++o) acc2[o] = vsplat(0.f);

        PAIR4(0,  w0, w1, w2, w3, w4, w5, w6);
        PAIR4(1,  w1, w2, w3, w4, w5, w6, w0);
        PAIR4(2,  w2, w3, w4, w5, w6, w0, w1);
        PAIR4(3,  w3, w4, w5, w6, w0, w1, w2);
        PAIR4(4,  w4, w5, w6, w0, w1, w2, w3);
        PAIR4(5,  w5, w6, w0, w1, w2, w3, w4);
        PAIR4(6,  w6, w0, w1, w2, w3, w4, w5);
        PAIR4(7,  w0, w1, w2, w3, w4, w5, w6);
        PAIR4(8,  w1, w2, w3, w4, w5, w6, w0);
        PAIR4(9,  w2, w3, w4, w5, w6, w0, w1);
        PAIR4(10, w3, w4, w5, w6, w0, w1, w2);
        PAIR4(11, w4, w5, w6, w0, w1, w2, w3);
        PAIR4(12, w5, w6, w0, w1, w2, w3, w4);
        PAIR4(13, w6, w0, w1, w2, w3, w4, w5);
        PAIR4(14, w0, w1, w2, w3, w4, w5, w6);
        ALIGNED(60, w1, w2, w3, w4, w5, w6);   // taps 15..20
    }
    __syncthreads();   // all tH reads complete before any t2 write (overlay)

    if (act2) {
        float* __restrict__ tw = &buf[lh * 54 + 26 * p];    // t2 region
#pragma unroll
        for (int o = 0; o < 26; ++o) tw[o] = acc2[o].x + acc2[o].y;
    }
    __syncthreads();

    // ---------------- Pass 3: downsample along H (col-pair packed) ----------------
    if (tid < 208) {
        const int c3 = tid % 26;        // out col pair -> cols 2c3, 2c3+1
        const int s3 = tid / 26;        // 0..7; out rows 7s..7s+6 (guarded)
        const float* __restrict__ p3b = &buf[(14 * s3) * 54 + 2 * c3];

        v2f r0, r1, r2, r3, r4, r5, r6, r7, r8, r9, r10, r11;
        P3LD(r0, r1, 0)  P3LD(r2, r3, 2)  P3LD(r4, r5, 4)
        P3LD(r6, r7, 6)  P3LD(r8, r9, 8)  P3LD(r10, r11, 10)

        P3OUT(0, r0, r1, r2, r3, r4, r5, r6, r7, r8, r9, r10, r11);
        P3LD(r0, r1, 12)
        P3OUT(1, r2, r3, r4, r5, r6, r7, r8, r9, r10, r11, r0, r1);
        P3LD(r2, r3, 14)
        P3OUT(2, r4, r5, r6, r7, r8, r9, r10, r11, r0, r1, r2, r3);
        P3LD(r4, r5, 16)
        P3OUT(3, r6, r7, r8, r9, r10, r11, r0, r1, r2, r3, r4, r5);
        P3LD(r6, r7, 18)
        P3OUT(4, r8, r9, r10, r11, r0, r1, r2, r3, r4, r5, r6, r7);
        P3LD(r8, r9, 20)
        P3OUT(5, r10, r11, r0, r1, r2, r3, r4, r5, r6, r7, r8, r9);
        P3LD(r10, r11, 22)
        P3OUT(6, r0, r1, r2, r3, r4, r5, r6, r7, r8, r9, r10, r11);
    }
}

extern "C" void kernel_launch(void* const* d_in, const int* in_sizes, int n_in,
                              void* d_out, int out_size, void* d_ws, size_t ws_size,
                              hipStream_t stream)
{
    const float* x  = (const float*)d_in[0];   // (16,512,36,36)
    const float* up = (const float*)d_in[1];   // (24,)
    const float* dn = (const float*)d_in[2];   // (12,)
    float* out = (float*)d_out;                // (16,512,52,52)

    afa_kernel<<<dim3(16 * 512), dim3(256), 0, stream>>>(x, up, dn, out);
}